// Round 1
// baseline (280.518 us; speedup 1.0000x reference)
//
#include <hip/hip_runtime.h>
#include <cmath>

#define EPSN 1e-12f
#define NT 1024      // threads in the train kernel
#define NSLOT 16     // Y / NT = 16384 / 1024
#define MAPCAP 32

__device__ __forceinline__ void amax_combine(float& v, int& i, float ov, int oi) {
    // jnp.argmax semantics: max value, first (lowest) index on ties
    if (ov > v || (ov == v && oi < i)) { v = ov; i = oi; }
}

// K1: per-row dot(W[i], x) and ||W[i]||^2 for x2y_w (Y x X). One block per row.
__global__ __launch_bounds__(256) void k_x2y(const float* __restrict__ W,
                                             const float* __restrict__ x,
                                             float* __restrict__ dotx,
                                             float* __restrict__ nw2,
                                             int X) {
    const int row = blockIdx.x;
    const float4* w4 = (const float4*)(W + (size_t)row * X);
    const float4* x4 = (const float4*)x;
    const int n4 = X >> 2;
    float d = 0.f, q = 0.f;
    for (int i = threadIdx.x; i < n4; i += 256) {
        float4 w = w4[i]; float4 xx = x4[i];
        d += w.x*xx.x + w.y*xx.y + w.z*xx.z + w.w*xx.w;
        q += w.x*w.x + w.y*w.y + w.z*w.z + w.w*w.w;
    }
    for (int off = 32; off; off >>= 1) {
        d += __shfl_down(d, off, 64);
        q += __shfl_down(q, off, 64);
    }
    __shared__ float sd[4], sq[4];
    const int w = threadIdx.x >> 6, lane = threadIdx.x & 63;
    if (lane == 0) { sd[w] = d; sq[w] = q; }
    __syncthreads();
    if (threadIdx.x == 0) {
        dotx[row] = sd[0] + sd[1] + sd[2] + sd[3];
        nw2[row]  = sq[0] + sq[1] + sq[2] + sq[3];
    }
}

// K2: per-row ||z2y_w[i]||^2 and z2y_w[i, z]. One wave per row, 4 rows/block.
__global__ __launch_bounds__(256) void k_z2y(const float* __restrict__ Wz,
                                             const int* __restrict__ zptr,
                                             float* __restrict__ valz,
                                             float* __restrict__ nz2,
                                             int Z) {
    const int zv = zptr[0];
    const int row = blockIdx.x * 4 + (threadIdx.x >> 6);
    const int lane = threadIdx.x & 63;
    const float* r = Wz + (size_t)row * Z;
    float q = 0.f, v = 0.f;
    for (int j = lane; j < Z; j += 64) {
        float e = r[j];
        q += e * e;
        if (j == zv) v = e;
    }
    for (int off = 32; off; off >>= 1) {
        q += __shfl_down(q, off, 64);
        v += __shfl_down(v, off, 64);
    }
    if (lane == 0) { nz2[row] = q; valz[row] = v; }
}

// K3: per-row ||y2z_w[k]||^2 (Z rows of length Y). One block per row.
__global__ __launch_bounds__(256) void k_y2z(const float* __restrict__ Wy,
                                             float* __restrict__ nry, int Y) {
    const int row = blockIdx.x;
    const float4* r4 = (const float4*)(Wy + (size_t)row * Y);
    const int n4 = Y >> 2;
    float q = 0.f;
    for (int i = threadIdx.x; i < n4; i += 256) {
        float4 w = r4[i];
        q += w.x*w.x + w.y*w.y + w.z*w.z + w.w*w.w;
    }
    for (int off = 32; off; off >>= 1) q += __shfl_down(q, off, 64);
    __shared__ float sqs[4];
    const int w = threadIdx.x >> 6, lane = threadIdx.x & 63;
    if (lane == 0) sqs[w] = q;
    __syncthreads();
    if (threadIdx.x == 0) nry[row] = sqs[0] + sqs[1] + sqs[2] + sqs[3];
}

// K4: the whole 10-step train loop + final output, single block of 1024.
// Each thread owns NSLOT=16 neuron indices (idx = j*NT + tid) holding
// cosines c (x-side), s (z-side), age, thr in registers.
__global__ __launch_bounds__(NT) void k_train(
    const float* __restrict__ x,
    const int* __restrict__ zptr,
    const int* __restrict__ pitem,
    const float* __restrict__ y2z,
    const float* __restrict__ age_y_in,
    const float* __restrict__ age_z_in,
    const float* __restrict__ thr_in,
    const float* __restrict__ dotx,
    const float* __restrict__ nw2,
    const float* __restrict__ valz,
    const float* __restrict__ nz2,
    const float* __restrict__ nry,
    float* __restrict__ out,
    int X, int Y, int Z)
{
    __shared__ float s_v1[NT/64]; __shared__ int s_i1[NT/64];
    __shared__ float s_v2[NT/64]; __shared__ int s_i2[NT/64];
    __shared__ float s_sum[NT/64];
    __shared__ float sh_xn, sh_r0, sh_thr0, sh_age0, sh_outz, sh_actn;
    __shared__ int sh_i0, sh_alti, sh_win, sh_winf, sh_cnt;

    const int tid = threadIdx.x;
    const int zv = zptr[0];

    // ---- Phase A: ||x||
    float q = 0.f;
    for (int i = tid; i < (X >> 2); i += NT) {
        float4 xx = ((const float4*)x)[i];
        q += xx.x*xx.x + xx.y*xx.y + xx.z*xx.z + xx.w*xx.w;
    }
    for (int off = 32; off; off >>= 1) q += __shfl_down(q, off, 64);
    if ((tid & 63) == 0) s_sum[tid >> 6] = q;
    __syncthreads();
    if (tid == 0) {
        float t = 0.f;
        for (int w = 0; w < NT/64; ++w) t += s_sum[w];
        sh_xn = fmaxf(sqrtf(t), EPSN);
    }
    __syncthreads();
    const float xn = sh_xn;

    // ---- Phase B: load per-neuron state into registers
    float c[NSLOT], s[NSLOT], age[NSLOT], thr[NSLOT];
    int cntloc = 0;
#pragma unroll
    for (int j = 0; j < NSLOT; ++j) {
        const int idx = j*NT + tid;
        c[j]   = dotx[idx] / (fmaxf(sqrtf(nw2[idx]), EPSN) * xn);
        s[j]   = valz[idx] / fmaxf(sqrtf(nz2[idx]), EPSN);
        age[j] = age_y_in[idx];
        thr[j] = thr_in[idx];
        if (age[j] < 1.0f) cntloc++;
    }
    __syncthreads();   // protect s_sum reuse
    {
        float cf = (float)cntloc;
        for (int off = 32; off; off >>= 1) cf += __shfl_down(cf, off, 64);
        if ((tid & 63) == 0) s_sum[tid >> 6] = cf;
    }
    __syncthreads();
    if (tid == 0) {
        float t = 0.f;
        for (int w = 0; w < NT/64; ++w) t += s_sum[w];
        sh_cnt = (int)(t + 0.5f);
    }

    // ---- thread-0 state for y2z row z: v = beta*v0 + sparse gamma
    float beta = 1.f, A = 0.f, B = 0.f, N0sq = 0.f, agez = 0.f;
    int mapn = 0; int midx[MAPCAP]; float mg[MAPCAP], mv0[MAPCAP];
    if (tid == 0) { N0sq = nry[zv]; agez = age_z_in[zv]; }
    __syncthreads();

    // ---- Main train loop
    const int PI = pitem[0];
    for (int t = 0; t < PI; ++t) {
        float bv = -INFINITY; int bi = 0x7fffffff;   // global argmax of y_pre
        float mvv = -INFINITY; int mii = 0x7fffffff; // argmax of y_pre * unact
#pragma unroll
        for (int j = 0; j < NSLOT; ++j) {
            const int idx = j*NT + tid;
            const float yp = 0.5f*c[j] + 0.5f*s[j];
            amax_combine(bv, bi, yp, idx);
            const float m = (age[j] < 1.0f) ? yp : yp * 0.0f;  // mask by multiplication (jnp)
            amax_combine(mvv, mii, m, idx);
        }
        for (int off = 32; off; off >>= 1) {
            float a = __shfl_down(bv, off, 64); int b = __shfl_down(bi, off, 64);
            amax_combine(bv, bi, a, b);
            float cc = __shfl_down(mvv, off, 64); int dd = __shfl_down(mii, off, 64);
            amax_combine(mvv, mii, cc, dd);
        }
        if ((tid & 63) == 0) {
            const int w = tid >> 6;
            s_v1[w] = bv; s_i1[w] = bi; s_v2[w] = mvv; s_i2[w] = mii;
        }
        __syncthreads();
        if (tid == 0) {
            float v = s_v1[0]; int i = s_i1[0];
            float v2 = s_v2[0]; int i2 = s_i2[0];
            for (int w = 1; w < NT/64; ++w) {
                amax_combine(v, i, s_v1[w], s_i1[w]);
                amax_combine(v2, i2, s_v2[w], s_i2[w]);
            }
            sh_r0 = v; sh_i0 = i; sh_alti = i2;
        }
        __syncthreads();
        const int i0 = sh_i0;
        if (tid == (i0 & (NT-1))) {
            const int slot = i0 >> 10;
#pragma unroll
            for (int j = 0; j < NSLOT; ++j) if (j == slot) { sh_thr0 = thr[j]; sh_age0 = age[j]; }
        }
        __syncthreads();
        if (tid == 0) {
            const bool keep = (sh_r0 > sh_thr0) || (sh_age0 < 1.0f);
            sh_win = keep ? i0 : (sh_cnt > 0 ? sh_alti : i0);
        }
        __syncthreads();
        const int win = sh_win;
        const float r0 = sh_r0;
        if (tid == (win & (NT-1))) {
            const int slot = win >> 10;
#pragma unroll
            for (int j = 0; j < NSLOT; ++j) if (j == slot) {
                const float a_old = age[j];
                const float lr = 1.0f/(a_old + 1.0f);
                const float om = 1.0f - lr;
                const float cj = c[j];
                c[j] = (om*cj + lr) / fmaxf(sqrtf(om*om + lr*lr + 2.0f*lr*om*cj), EPSN);
                const float sj = s[j];
                s[j] = (om*sj + lr) / fmaxf(sqrtf(om*om + lr*lr + 2.0f*lr*om*sj), EPSN);
                thr[j] = lr*r0 + om*thr[j];
                age[j] = a_old + 1.0f;
                if (a_old < 1.0f && a_old + 1.0f >= 1.0f) sh_cnt -= 1;  // single writer
            }
        }
        if (tid == 0) {
            // normalize tracked y2z row z, then EMA toward e_win
            const float L = fmaxf(sqrtf(beta*beta*N0sq + 2.f*beta*A + B), EPSN);
            beta /= L; A /= L; B /= (L*L);
            for (int e = 0; e < mapn; ++e) mg[e] /= L;
            const float zlr = 1.0f/(agez + 1.0f);   // zh[0,z]=1
            const float oz = 1.0f - zlr;
            beta *= oz; A *= oz; B *= oz*oz;
            for (int e = 0; e < mapn; ++e) mg[e] *= oz;
            int e = 0;
            for (; e < mapn; ++e) if (midx[e] == win) break;
            if (e == mapn) {
                if (mapn < MAPCAP) {
                    midx[mapn] = win; mg[mapn] = 0.f;
                    mv0[mapn] = y2z[(size_t)zv*(size_t)Y + win];
                    mapn++;
                } else e = MAPCAP - 1;  // unreachable for per_item<=32
            }
            const float gold = mg[e];
            B += 2.f*zlr*gold + zlr*zlr;
            A += zlr*mv0[e];
            mg[e] = gold + zlr;
            agez += 1.0f;
        }
        __syncthreads();
    }

    // ---- Final: y_temp = c * (age>=1), argmax; activated count; output column
    float bv = -INFINITY; int bi = 0x7fffffff;
    float fcnt = 0.f;
#pragma unroll
    for (int j = 0; j < NSLOT; ++j) {
        const int idx = j*NT + tid;
        const float flag = (age[j] >= 1.0f) ? 1.0f : 0.0f;
        amax_combine(bv, bi, c[j]*flag, idx);
        fcnt += flag;
    }
    for (int off = 32; off; off >>= 1) {
        float a = __shfl_down(bv, off, 64); int b = __shfl_down(bi, off, 64);
        amax_combine(bv, bi, a, b);
        fcnt += __shfl_down(fcnt, off, 64);
    }
    if ((tid & 63) == 0) {
        const int w = tid >> 6;
        s_v1[w] = bv; s_i1[w] = bi; s_sum[w] = fcnt;
    }
    __syncthreads();
    if (tid == 0) {
        float v = s_v1[0]; int i = s_i1[0]; float t = s_sum[0];
        for (int w = 1; w < NT/64; ++w) { amax_combine(v, i, s_v1[w], s_i1[w]); t += s_sum[w]; }
        sh_winf = i; sh_actn = t;
        // out[z] from tracked sparse row (final l2n applied)
        const float L = fmaxf(sqrtf(beta*beta*N0sq + 2.f*beta*A + B), EPSN);
        float g = 0.f, v0wf;
        int e = 0;
        for (; e < mapn; ++e) if (midx[e] == i) break;
        if (e < mapn) { g = mg[e]; v0wf = mv0[e]; }
        else v0wf = y2z[(size_t)zv*(size_t)Y + i];
        sh_outz = (beta*v0wf + g) / L;
    }
    __syncthreads();
    if (tid < Z) {
        float o;
        if (tid == zv) o = sh_outz;
        else o = y2z[(size_t)tid*(size_t)Y + sh_winf] / fmaxf(sqrtf(nry[tid]), EPSN);
        out[tid] = o;
    }
    if (tid == 0) out[Z] = sh_actn;
}

extern "C" void kernel_launch(void* const* d_in, const int* in_sizes, int n_in,
                              void* d_out, int out_size, void* d_ws, size_t ws_size,
                              hipStream_t stream) {
    const float* x    = (const float*)d_in[0];
    const int*   z    = (const int*)d_in[1];
    const int*   pit  = (const int*)d_in[2];
    const float* x2y  = (const float*)d_in[3];
    const float* z2y  = (const float*)d_in[4];
    const float* y2z  = (const float*)d_in[5];
    const float* agey = (const float*)d_in[6];
    const float* agez = (const float*)d_in[7];
    const float* thr  = (const float*)d_in[8];
    const int X = in_sizes[0];   // 4096
    const int Y = in_sizes[6];   // 16384 (= NT*NSLOT)
    const int Z = in_sizes[7];   // 100

    float* ws   = (float*)d_ws;
    float* dotx = ws;
    float* nw2  = ws + Y;
    float* valz = ws + 2*(size_t)Y;
    float* nz2  = ws + 3*(size_t)Y;
    float* nry  = ws + 4*(size_t)Y;
    float* out  = (float*)d_out;

    hipLaunchKernelGGL(k_x2y, dim3(Y), dim3(256), 0, stream, x2y, x, dotx, nw2, X);
    hipLaunchKernelGGL(k_z2y, dim3(Y/4), dim3(256), 0, stream, z2y, z, valz, nz2, Z);
    hipLaunchKernelGGL(k_y2z, dim3(Z), dim3(256), 0, stream, y2z, nry, Y);
    hipLaunchKernelGGL(k_train, dim3(1), dim3(NT), 0, stream,
                       x, z, pit, y2z, agey, agez, thr,
                       dotx, nw2, valz, nz2, nry, out, X, Y, Z);
}

// Round 2
// 142.051 us; speedup vs baseline: 1.9748x; 1.9748x over previous
//
#include <hip/hip_runtime.h>
#include <cmath>

#define EPSN 1e-12f
#define NT 1024          // threads in the train kernel
#define YTOT 16384
#define NWAVE (NT/64)    // 16
#define MAPCAP 16

__device__ __forceinline__ void amax_combine(float& v, int& i, float ov, int oi) {
    // jnp.argmax semantics: max value, first (lowest) index on ties
    if (ov > v || (ov == v && oi < i)) { v = ov; i = oi; }
}

// K1: per-row dot(W[i], x) and ||W[i]||^2 for x2y_w (Y x X). One block per row.
__global__ __launch_bounds__(256) void k_x2y(const float* __restrict__ W,
                                             const float* __restrict__ x,
                                             float* __restrict__ dotx,
                                             float* __restrict__ nw2,
                                             int X) {
    const int row = blockIdx.x;
    const float4* w4 = (const float4*)(W + (size_t)row * X);
    const float4* x4 = (const float4*)x;
    const int n4 = X >> 2;
    float d = 0.f, q = 0.f;
    for (int i = threadIdx.x; i < n4; i += 256) {
        float4 w = w4[i]; float4 xx = x4[i];
        d += w.x*xx.x + w.y*xx.y + w.z*xx.z + w.w*xx.w;
        q += w.x*w.x + w.y*w.y + w.z*w.z + w.w*w.w;
    }
    for (int off = 32; off; off >>= 1) {
        d += __shfl_down(d, off, 64);
        q += __shfl_down(q, off, 64);
    }
    __shared__ float sd[4], sq[4];
    const int w = threadIdx.x >> 6, lane = threadIdx.x & 63;
    if (lane == 0) { sd[w] = d; sq[w] = q; }
    __syncthreads();
    if (threadIdx.x == 0) {
        dotx[row] = sd[0] + sd[1] + sd[2] + sd[3];
        nw2[row]  = sq[0] + sq[1] + sq[2] + sq[3];
    }
}

// K2: per-row ||z2y_w[i]||^2 and z2y_w[i, z]. One wave per row, 4 rows/block.
__global__ __launch_bounds__(256) void k_z2y(const float* __restrict__ Wz,
                                             const int* __restrict__ zptr,
                                             float* __restrict__ valz,
                                             float* __restrict__ nz2,
                                             int Z) {
    const int zv = zptr[0];
    const int row = blockIdx.x * 4 + (threadIdx.x >> 6);
    const int lane = threadIdx.x & 63;
    const float* r = Wz + (size_t)row * Z;
    float q = 0.f, v = 0.f;
    for (int j = lane; j < Z; j += 64) {
        float e = r[j];
        q += e * e;
        if (j == zv) v = e;
    }
    for (int off = 32; off; off >>= 1) {
        q += __shfl_down(q, off, 64);
        v += __shfl_down(v, off, 64);
    }
    if (lane == 0) { nz2[row] = q; valz[row] = v; }
}

// K3: per-row ||y2z_w[k]||^2 (Z rows of length Y). One block per row.
__global__ __launch_bounds__(256) void k_y2z(const float* __restrict__ Wy,
                                             float* __restrict__ nry, int Y) {
    const int row = blockIdx.x;
    const float4* r4 = (const float4*)(Wy + (size_t)row * Y);
    const int n4 = Y >> 2;
    float q = 0.f;
    for (int i = threadIdx.x; i < n4; i += 256) {
        float4 w = r4[i];
        q += w.x*w.x + w.y*w.y + w.z*w.z + w.w*w.w;
    }
    for (int off = 32; off; off >>= 1) q += __shfl_down(q, off, 64);
    __shared__ float sqs[4];
    const int w = threadIdx.x >> 6, lane = threadIdx.x & 63;
    if (lane == 0) sqs[w] = q;
    __syncthreads();
    if (threadIdx.x == 0) nry[row] = sqs[0] + sqs[1] + sqs[2] + sqs[3];
}

// K4: whole 10-step train loop + final output, single block of 1024.
// ALL per-neuron state lives in LDS (yp = pre-response, cA = x-cosine,
// young = age<1 bitmask). Per-thread registers hold only scalars -> no spill.
__global__ __launch_bounds__(NT) void k_train(
    const float* __restrict__ x,
    const int* __restrict__ zptr,
    const int* __restrict__ pitem,
    const float* __restrict__ y2z,
    const float* __restrict__ age_y_in,
    const float* __restrict__ age_z_in,
    const float* __restrict__ thr_in,
    const float* __restrict__ dotx,
    const float* __restrict__ nw2,
    const float* __restrict__ valz,
    const float* __restrict__ nz2,
    const float* __restrict__ nry,
    float* __restrict__ out,
    int X, int Y, int Z)
{
    __shared__ __align__(16) float yp[YTOT];    // 64 KB: 0.5*(c+s), live argmax target
    __shared__ __align__(16) float cA[YTOT];    // 64 KB: current x-cosine per neuron
    __shared__ unsigned young[YTOT/32];         // 2 KB: bit=1 iff age<1
    __shared__ float s_v1[NWAVE]; __shared__ int s_i1[NWAVE];
    __shared__ float s_v2[NWAVE]; __shared__ int s_i2[NWAVE];
    __shared__ float s_sum[NWAVE];
    __shared__ float sh_xn, sh_outz, sh_actn;
    __shared__ int sh_winf, sh_cnt;
    // winner map (rows that won at least once): current age/thr/s
    __shared__ int   wm_idx[MAPCAP];
    __shared__ float wm_age[MAPCAP], wm_thr[MAPCAP], wm_s[MAPCAP];
    // y2z sparse-row map: v_z = beta*v0 + sum_e g[e]*e_{idx[e]}
    __shared__ int   ym_idx[MAPCAP];
    __shared__ float ym_g[MAPCAP], ym_v0[MAPCAP];

    const int tid = threadIdx.x;
    const int lane = tid & 63;
    const int wv = tid >> 6;
    const int zv = zptr[0];

    // ---- Phase A: ||x||
    {
        float q = 0.f;
        for (int i = tid; i < (X >> 2); i += NT) {
            float4 xx = ((const float4*)x)[i];
            q += xx.x*xx.x + xx.y*xx.y + xx.z*xx.z + xx.w*xx.w;
        }
        for (int off = 32; off; off >>= 1) q += __shfl_down(q, off, 64);
        if (lane == 0) s_sum[wv] = q;
    }
    if (tid == 0) sh_cnt = 0;
    for (int w = tid; w < YTOT/32; w += NT) young[w] = 0u;
    __syncthreads();
    if (tid == 0) {
        float t = 0.f;
        for (int w = 0; w < NWAVE; ++w) t += s_sum[w];
        sh_xn = fmaxf(sqrtf(t), EPSN);
    }
    __syncthreads();
    const float xn = sh_xn;

    // ---- Phase B: build yp / cA / young in LDS (vectorized)
    {
        int myy = 0;
        for (int i = tid; i < YTOT/4; i += NT) {   // 4 iters/thread
            float4 dx = ((const float4*)dotx)[i];
            float4 nw = ((const float4*)nw2)[i];
            float4 vz = ((const float4*)valz)[i];
            float4 nz = ((const float4*)nz2)[i];
            float4 ag = ((const float4*)age_y_in)[i];
            float c0 = dx.x / (fmaxf(sqrtf(nw.x), EPSN) * xn);
            float c1 = dx.y / (fmaxf(sqrtf(nw.y), EPSN) * xn);
            float c2 = dx.z / (fmaxf(sqrtf(nw.z), EPSN) * xn);
            float c3 = dx.w / (fmaxf(sqrtf(nw.w), EPSN) * xn);
            float s0 = vz.x / fmaxf(sqrtf(nz.x), EPSN);
            float s1 = vz.y / fmaxf(sqrtf(nz.y), EPSN);
            float s2 = vz.z / fmaxf(sqrtf(nz.z), EPSN);
            float s3 = vz.w / fmaxf(sqrtf(nz.w), EPSN);
            ((float4*)cA)[i] = make_float4(c0, c1, c2, c3);
            ((float4*)yp)[i] = make_float4(0.5f*(c0+s0), 0.5f*(c1+s1),
                                           0.5f*(c2+s2), 0.5f*(c3+s3));
            unsigned bits = (ag.x < 1.0f ? 1u : 0u) | (ag.y < 1.0f ? 2u : 0u)
                          | (ag.z < 1.0f ? 4u : 0u) | (ag.w < 1.0f ? 8u : 0u);
            myy += __popc(bits);
            if (bits) atomicOr(&young[i >> 3], bits << ((i & 7) * 4));
        }
        for (int off = 32; off; off >>= 1) myy += __shfl_down(myy, off, 64);
        if (lane == 0) atomicAdd(&sh_cnt, myy);
    }
    __syncthreads();

    // ---- thread-0 persistent scalars
    int   cnt = sh_cnt;          // only thread 0 uses these
    int   wm_n = 0, ym_n = 0;
    float beta = 1.f, Aacc = 0.f, Bacc = 0.f, N0sq = 0.f, agez = 0.f;
    if (tid == 0) { N0sq = nry[zv]; agez = age_z_in[zv]; }

    // ---- Main train loop
    const int PI = pitem[0];
    for (int t = 0; t < PI; ++t) {
        float bv = -INFINITY; int bi = 0x7fffffff;   // argmax y_pre
        float mv = -INFINITY; int mi = 0x7fffffff;   // argmax y_pre*unact
#pragma unroll
        for (int j = 0; j < YTOT/NT; ++j) {
            const int idx = j*NT + tid;
            const float v = yp[idx];
            amax_combine(bv, bi, v, idx);
            const unsigned w = young[idx >> 5];
            const float m = v * (((w >> (tid & 31)) & 1u) ? 1.0f : 0.0f);
            amax_combine(mv, mi, m, idx);
        }
        for (int off = 32; off; off >>= 1) {
            float a = __shfl_down(bv, off, 64); int b = __shfl_down(bi, off, 64);
            amax_combine(bv, bi, a, b);
            float cc = __shfl_down(mv, off, 64); int dd = __shfl_down(mi, off, 64);
            amax_combine(mv, mi, cc, dd);
        }
        if (lane == 0) { s_v1[wv] = bv; s_i1[wv] = bi; s_v2[wv] = mv; s_i2[wv] = mi; }
        __syncthreads();
        if (tid == 0) {
            float r0 = s_v1[0]; int i0 = s_i1[0];
            float av = s_v2[0]; int alt = s_i2[0];
            for (int w = 1; w < NWAVE; ++w) {
                amax_combine(r0, i0, s_v1[w], s_i1[w]);
                amax_combine(av, alt, s_v2[w], s_i2[w]);
            }
            // thr/age of candidate i0 (winner map first, else global)
            int e0 = 0; for (; e0 < wm_n; ++e0) if (wm_idx[e0] == i0) break;
            float age0, thr0;
            if (e0 < wm_n) { age0 = wm_age[e0]; thr0 = wm_thr[e0]; }
            else           { age0 = age_y_in[i0]; thr0 = thr_in[i0]; }
            const bool keep = (r0 > thr0) || (age0 < 1.0f);
            const int win = keep ? i0 : (cnt > 0 ? alt : i0);
            // winner current state
            int e = 0; for (; e < wm_n; ++e) if (wm_idx[e] == win) break;
            float age_o, thr_o, s_o;
            if (e < wm_n) { age_o = wm_age[e]; thr_o = wm_thr[e]; s_o = wm_s[e]; }
            else {
                if (win == i0) { age_o = age0; thr_o = thr0; }
                else { age_o = age_y_in[win]; thr_o = thr_in[win]; }
                s_o = valz[win] / fmaxf(sqrtf(nz2[win]), EPSN);
                wm_idx[wm_n] = win; e = wm_n; wm_n++;
            }
            const float c_o = cA[win];
            const float lr = 1.0f / (age_o + 1.0f);
            const float om = 1.0f - lr;
            const float c_n = (om*c_o + lr) / fmaxf(sqrtf(om*om + lr*lr + 2.f*lr*om*c_o), EPSN);
            const float s_n = (om*s_o + lr) / fmaxf(sqrtf(om*om + lr*lr + 2.f*lr*om*s_o), EPSN);
            wm_age[e] = age_o + 1.0f;
            wm_thr[e] = lr*r0 + om*thr_o;
            wm_s[e]   = s_n;
            cA[win] = c_n;
            yp[win] = 0.5f*(c_n + s_n);
            if (age_o < 1.0f && age_o + 1.0f >= 1.0f) {
                young[win >> 5] &= ~(1u << (win & 31));
                cnt -= 1;
            }
            // y2z tracked row z: normalize then EMA toward e_win
            {
                const float L = fmaxf(sqrtf(beta*beta*N0sq + 2.f*beta*Aacc + Bacc), EPSN);
                beta /= L; Aacc /= L; Bacc /= (L*L);
                for (int k = 0; k < ym_n; ++k) ym_g[k] /= L;
                const float zlr = 1.0f / (agez + 1.0f);
                const float oz = 1.0f - zlr;
                beta *= oz; Aacc *= oz; Bacc *= oz*oz;
                for (int k = 0; k < ym_n; ++k) ym_g[k] *= oz;
                int k = 0; for (; k < ym_n; ++k) if (ym_idx[k] == win) break;
                if (k == ym_n) {
                    ym_idx[ym_n] = win; ym_g[ym_n] = 0.f;
                    ym_v0[ym_n] = y2z[(size_t)zv * (size_t)Y + win];
                    ym_n++;
                }
                const float gold = ym_g[k];
                Bacc += 2.f*zlr*gold + zlr*zlr;
                Aacc += zlr*ym_v0[k];
                ym_g[k] = gold + zlr;
                agez += 1.0f;
            }
        }
        __syncthreads();
    }

    // ---- Final: argmax over cA * activated, count, output column
    {
        float bv = -INFINITY; int bi = 0x7fffffff;
#pragma unroll
        for (int j = 0; j < YTOT/NT; ++j) {
            const int idx = j*NT + tid;
            const unsigned w = young[idx >> 5];
            const float flag = (((w >> (tid & 31)) & 1u) ? 0.0f : 1.0f);
            amax_combine(bv, bi, cA[idx] * flag, idx);
        }
        for (int off = 32; off; off >>= 1) {
            float a = __shfl_down(bv, off, 64); int b = __shfl_down(bi, off, 64);
            amax_combine(bv, bi, a, b);
        }
        if (lane == 0) { s_v1[wv] = bv; s_i1[wv] = bi; }
    }
    __syncthreads();
    if (tid == 0) {
        float v = s_v1[0]; int i = s_i1[0];
        for (int w = 1; w < NWAVE; ++w) amax_combine(v, i, s_v1[w], s_i1[w]);
        sh_winf = i;
        sh_actn = (float)YTOT - (float)cnt;
        const float L = fmaxf(sqrtf(beta*beta*N0sq + 2.f*beta*Aacc + Bacc), EPSN);
        float g = 0.f, v0wf;
        int k = 0; for (; k < ym_n; ++k) if (ym_idx[k] == i) break;
        if (k < ym_n) { g = ym_g[k]; v0wf = ym_v0[k]; }
        else v0wf = y2z[(size_t)zv * (size_t)Y + i];
        sh_outz = (beta*v0wf + g) / L;
    }
    __syncthreads();
    if (tid < Z) {
        float o;
        if (tid == zv) o = sh_outz;
        else o = y2z[(size_t)tid * (size_t)Y + sh_winf] / fmaxf(sqrtf(nry[tid]), EPSN);
        out[tid] = o;
    }
    if (tid == 0) out[Z] = sh_actn;
}

extern "C" void kernel_launch(void* const* d_in, const int* in_sizes, int n_in,
                              void* d_out, int out_size, void* d_ws, size_t ws_size,
                              hipStream_t stream) {
    const float* x    = (const float*)d_in[0];
    const int*   z    = (const int*)d_in[1];
    const int*   pit  = (const int*)d_in[2];
    const float* x2y  = (const float*)d_in[3];
    const float* z2y  = (const float*)d_in[4];
    const float* y2z  = (const float*)d_in[5];
    const float* agey = (const float*)d_in[6];
    const float* agez = (const float*)d_in[7];
    const float* thr  = (const float*)d_in[8];
    const int X = in_sizes[0];   // 4096
    const int Y = in_sizes[6];   // 16384
    const int Z = in_sizes[7];   // 100

    float* ws   = (float*)d_ws;
    float* dotx = ws;
    float* nw2  = ws + Y;
    float* valz = ws + 2*(size_t)Y;
    float* nz2  = ws + 3*(size_t)Y;
    float* nry  = ws + 4*(size_t)Y;
    float* out  = (float*)d_out;

    hipLaunchKernelGGL(k_x2y, dim3(Y), dim3(256), 0, stream, x2y, x, dotx, nw2, X);
    hipLaunchKernelGGL(k_z2y, dim3(Y/4), dim3(256), 0, stream, z2y, z, valz, nz2, Z);
    hipLaunchKernelGGL(k_y2z, dim3(Z), dim3(256), 0, stream, y2z, nry, Y);
    hipLaunchKernelGGL(k_train, dim3(1), dim3(NT), 0, stream,
                       x, z, pit, y2z, agey, agez, thr,
                       dotx, nw2, valz, nz2, nry, out, X, Y, Z);
}

// Round 3
// 103.504 us; speedup vs baseline: 2.7102x; 1.3724x over previous
//
#include <hip/hip_runtime.h>
#include <cmath>

#define EPSN 1e-12f
#define NT 1024          // threads in the train kernel
#define YTOT 16384
#define NWAVE (NT/64)    // 16
#define MAPCAP 32

__device__ __forceinline__ void amax_combine(float& v, int& i, float ov, int oi) {
    // jnp.argmax semantics: max value, first (lowest) index on ties
    if (ov > v || (ov == v && oi < i)) { v = ov; i = oi; }
}

// Fused prep: z2y row stats (blocks [0, Y/4)), y2z row norms ([Y/4, Y/4+Z)),
// x2y row dot+norm2 (the rest, one block per row).
__global__ __launch_bounds__(256) void k_prep(
    const float* __restrict__ x2y, const float* __restrict__ z2y,
    const float* __restrict__ y2z, const int* __restrict__ zptr,
    const float* __restrict__ x,
    float* __restrict__ dotx, float* __restrict__ nw2,
    float* __restrict__ valz, float* __restrict__ nz2,
    float* __restrict__ nry, int X, int Y, int Z)
{
    const int bid = blockIdx.x;
    const int NBZ = Y / 4;
    const int tid = threadIdx.x;
    const int lane = tid & 63, wv = tid >> 6;
    if (bid < NBZ) {
        // z2y: 4 rows per block, one wave each
        const int zv = zptr[0];
        const int row = bid * 4 + wv;
        const float* r = z2y + (size_t)row * Z;
        float q = 0.f, v = 0.f;
        for (int j = lane; j < Z; j += 64) {
            float e = r[j];
            q += e * e;
            if (j == zv) v = e;
        }
        for (int off = 32; off; off >>= 1) {
            q += __shfl_down(q, off, 64);
            v += __shfl_down(v, off, 64);
        }
        if (lane == 0) { nz2[row] = q; valz[row] = v; }
    } else if (bid < NBZ + Z) {
        // y2z row norms
        const int row = bid - NBZ;
        const float4* r4 = (const float4*)(y2z + (size_t)row * Y);
        float q = 0.f;
        for (int i = tid; i < (Y >> 2); i += 256) {
            float4 w = r4[i];
            q += w.x*w.x + w.y*w.y + w.z*w.z + w.w*w.w;
        }
        for (int off = 32; off; off >>= 1) q += __shfl_down(q, off, 64);
        __shared__ float sq[4];
        if (lane == 0) sq[wv] = q;
        __syncthreads();
        if (tid == 0) nry[row] = sq[0] + sq[1] + sq[2] + sq[3];
    } else {
        // x2y: one row per block
        const int row = bid - NBZ - Z;
        const float4* w4 = (const float4*)(x2y + (size_t)row * X);
        const float4* x4 = (const float4*)x;
        float d = 0.f, q = 0.f;
        for (int i = tid; i < (X >> 2); i += 256) {
            float4 w = w4[i]; float4 xx = x4[i];
            d += w.x*xx.x + w.y*xx.y + w.z*xx.z + w.w*xx.w;
            q += w.x*w.x + w.y*w.y + w.z*w.z + w.w*w.w;
        }
        for (int off = 32; off; off >>= 1) {
            d += __shfl_down(d, off, 64);
            q += __shfl_down(q, off, 64);
        }
        __shared__ float sd[4], sq2[4];
        if (lane == 0) { sd[wv] = d; sq2[wv] = q; }
        __syncthreads();
        if (tid == 0) {
            dotx[row] = sd[0] + sd[1] + sd[2] + sd[3];
            nw2[row]  = sq2[0] + sq2[1] + sq2[2] + sq2[3];
        }
    }
}

// Winner-update routine, executed by thread 0 only. Uses thread0 scalar regs
// (cnt, wm_n, ym_n, beta, Aacc, Bacc, N0sq, agez, r0) + LDS maps. G0..G4 are
// the candidate's prefetched ORIGINAL thr/age/valz/nz2/y2z-elem.
#define CAND_UPDATE(WIN, G0, G1, G2, G3, G4) do { \
    const int win_ = (WIN); \
    float age_o = (G1), thr_o = (G0); \
    float s_o = (G2) / fmaxf(sqrtf(G3), EPSN); \
    for (int k_ = 0; k_ < wm_n; ++k_) if (wm_idx[k_] == win_) { \
        age_o = wm_age[k_]; thr_o = wm_thr[k_]; s_o = wm_s[k_]; break; } \
    const float lr_ = 1.0f/(age_o+1.0f), om_ = 1.0f-lr_; \
    const float co_ = cA[win_]; \
    const float cn_ = (om_*co_+lr_)/fmaxf(sqrtf(om_*om_+lr_*lr_+2.f*lr_*om_*co_), EPSN); \
    const float sn_ = (om_*s_o+lr_)/fmaxf(sqrtf(om_*om_+lr_*lr_+2.f*lr_*om_*s_o), EPSN); \
    int e_ = 0; for (; e_ < wm_n; ++e_) if (wm_idx[e_] == win_) break; \
    if (e_ == wm_n) { wm_idx[e_] = win_; wm_n++; } \
    wm_age[e_] = age_o + 1.0f; wm_thr[e_] = lr_*r0 + om_*thr_o; wm_s[e_] = sn_; \
    cA[win_] = cn_; yp[win_] = 0.5f*(cn_+sn_); \
    if (age_o < 1.0f && age_o + 1.0f >= 1.0f) { \
        young[win_>>5] &= ~(1u << (win_&31)); cnt--; } \
    const float L_ = fmaxf(sqrtf(beta*beta*N0sq + 2.f*beta*Aacc + Bacc), EPSN); \
    beta /= L_; Aacc /= L_; Bacc /= (L_*L_); \
    for (int k_ = 0; k_ < ym_n; ++k_) ym_g[k_] /= L_; \
    const float zlr_ = 1.0f/(agez+1.0f), oz_ = 1.0f-zlr_; \
    beta *= oz_; Aacc *= oz_; Bacc *= oz_*oz_; \
    for (int k_ = 0; k_ < ym_n; ++k_) ym_g[k_] *= oz_; \
    int q_ = 0; for (; q_ < ym_n; ++q_) if (ym_idx[q_] == win_) break; \
    if (q_ == ym_n) { ym_idx[q_] = win_; ym_g[q_] = 0.f; ym_v0[q_] = (G4); ym_n++; } \
    const float gold_ = ym_g[q_]; \
    Bacc += 2.f*zlr_*gold_ + zlr_*zlr_; \
    Aacc += zlr_*ym_v0[q_]; \
    ym_g[q_] = gold_ + zlr_; \
    agez += 1.0f; \
} while (0)

__global__ __launch_bounds__(NT) void k_train(
    const float* __restrict__ x, const int* __restrict__ zptr,
    const int* __restrict__ pitem, const float* __restrict__ y2z,
    const float* __restrict__ age_y_in, const float* __restrict__ age_z_in,
    const float* __restrict__ thr_in,
    const float* __restrict__ dotx, const float* __restrict__ nw2,
    const float* __restrict__ valz, const float* __restrict__ nz2,
    const float* __restrict__ nry,
    float* __restrict__ out, int X, int Y, int Z)
{
    __shared__ __align__(16) float yp[YTOT];    // 64 KB live pre-response
    __shared__ __align__(16) float cA[YTOT];    // 64 KB x-cosines
    __shared__ unsigned young[YTOT/32];         // 2 KB age<1 bitmask
    __shared__ float s_v1[NWAVE]; __shared__ int s_i1[NWAVE];
    __shared__ float s_v2[NWAVE]; __shared__ int s_i2[NWAVE];
    __shared__ float s_g1[NWAVE][5];            // prefetched thr/age/vz/nz/y2z per wave cand
    __shared__ float s_g2[NWAVE][5];
    __shared__ float s_sum[NWAVE];
    __shared__ int   wm_idx[MAPCAP];
    __shared__ float wm_age[MAPCAP], wm_thr[MAPCAP], wm_s[MAPCAP];
    __shared__ int   ym_idx[MAPCAP];
    __shared__ float ym_g[MAPCAP], ym_v0[MAPCAP];
    __shared__ float sh_xn, sh_outz, sh_actn;
    __shared__ int sh_flag, sh_winf, sh_cnt0;

    const int tid = threadIdx.x, lane = tid & 63, wv = tid >> 6;
    const int zv = zptr[0];
    const float* __restrict__ y2zrow = y2z + (size_t)zv * Y;

    // ---- Phase A: ||x|| partials + init
    {
        float q = 0.f;
        for (int i = tid; i < (X >> 2); i += NT) {
            float4 xx = ((const float4*)x)[i];
            q += xx.x*xx.x + xx.y*xx.y + xx.z*xx.z + xx.w*xx.w;
        }
        for (int off = 32; off; off >>= 1) q += __shfl_down(q, off, 64);
        if (lane == 0) s_sum[wv] = q;
    }
    if (tid == 0) sh_cnt0 = 0;
    for (int w = tid; w < YTOT/32; w += NT) young[w] = 0u;
    __syncthreads();
    if (tid == 0) {
        float t = 0.f;
        for (int w = 0; w < NWAVE; ++w) t += s_sum[w];
        sh_xn = fmaxf(sqrtf(t), EPSN);
    }
    __syncthreads();
    const float xn = sh_xn;

    // ---- Phase B: build yp/cA/young; warm thr + y2z[zv] row into local L2
    {
        int myy = 0; float warm = 0.f;
        for (int i = tid; i < YTOT/4; i += NT) {
            float4 dx = ((const float4*)dotx)[i];
            float4 nw = ((const float4*)nw2)[i];
            float4 vz = ((const float4*)valz)[i];
            float4 nz = ((const float4*)nz2)[i];
            float4 ag = ((const float4*)age_y_in)[i];
            float4 th = ((const float4*)thr_in)[i];
            float4 yz = ((const float4*)y2zrow)[i];
            warm += th.x+th.y+th.z+th.w + yz.x+yz.y+yz.z+yz.w;
            float c0 = dx.x / (fmaxf(sqrtf(nw.x), EPSN) * xn);
            float c1 = dx.y / (fmaxf(sqrtf(nw.y), EPSN) * xn);
            float c2 = dx.z / (fmaxf(sqrtf(nw.z), EPSN) * xn);
            float c3 = dx.w / (fmaxf(sqrtf(nw.w), EPSN) * xn);
            float s0 = vz.x / fmaxf(sqrtf(nz.x), EPSN);
            float s1 = vz.y / fmaxf(sqrtf(nz.y), EPSN);
            float s2 = vz.z / fmaxf(sqrtf(nz.z), EPSN);
            float s3 = vz.w / fmaxf(sqrtf(nz.w), EPSN);
            ((float4*)cA)[i] = make_float4(c0, c1, c2, c3);
            ((float4*)yp)[i] = make_float4(0.5f*(c0+s0), 0.5f*(c1+s1),
                                           0.5f*(c2+s2), 0.5f*(c3+s3));
            unsigned bits = (ag.x < 1.0f ? 1u : 0u) | (ag.y < 1.0f ? 2u : 0u)
                          | (ag.z < 1.0f ? 4u : 0u) | (ag.w < 1.0f ? 8u : 0u);
            myy += __popc(bits);
            if (bits) atomicOr(&young[i >> 3], bits << ((i & 7) * 4));
        }
        asm volatile("" :: "v"(warm));   // keep warming loads live (rule #17)
        for (int off = 32; off; off >>= 1) myy += __shfl_down(myy, off, 64);
        if (lane == 0) atomicAdd(&sh_cnt0, myy);
    }
    __syncthreads();

    // ---- thread-0 scalar state (registers)
    int   cnt = 0, wm_n = 0, ym_n = 0;
    float beta = 1.f, Aacc = 0.f, Bacc = 0.f, N0sq = 0.f, agez = 0.f;
    if (tid == 0) { cnt = sh_cnt0; N0sq = nry[zv]; agez = age_z_in[zv]; }

    float r0 = 0.f; int i0 = 0, w1 = 0;   // persist across the alt branch

    // ---- Main train loop
    const int PI = pitem[0];
    for (int t = 0; t < PI; ++t) {
        // full argmax sweep (strict > ok: idx ascending per thread)
        float bv = -INFINITY; int bi = 0;
#pragma unroll
        for (int j = 0; j < YTOT/NT; ++j) {
            const int idx = j*NT + tid;
            const float v = yp[idx];
            if (v > bv) { bv = v; bi = idx; }
        }
        for (int off = 32; off; off >>= 1) {
            float a = __shfl_down(bv, off, 64); int b = __shfl_down(bi, off, 64);
            amax_combine(bv, bi, a, b);
        }
        if (lane == 0) {
            s_v1[wv] = bv; s_i1[wv] = bi;
            // prefetch candidate originals in parallel with reduce+barrier
            s_g1[wv][0] = thr_in[bi]; s_g1[wv][1] = age_y_in[bi];
            s_g1[wv][2] = valz[bi];   s_g1[wv][3] = nz2[bi];
            s_g1[wv][4] = y2zrow[bi];
        }
        __syncthreads();
        if (tid == 0) {
            r0 = -INFINITY; i0 = 0x7fffffff; w1 = 0;
            for (int w = 0; w < NWAVE; ++w) {
                const float v = s_v1[w]; const int ii = s_i1[w];
                if (v > r0 || (v == r0 && ii < i0)) { r0 = v; i0 = ii; w1 = w; }
            }
            float age0 = s_g1[w1][1], thr0 = s_g1[w1][0];
            for (int k = 0; k < wm_n; ++k)
                if (wm_idx[k] == i0) { age0 = wm_age[k]; thr0 = wm_thr[k]; break; }
            const bool keep = (r0 > thr0) || (age0 < 1.0f);
            if (keep) {
                CAND_UPDATE(i0, s_g1[w1][0], s_g1[w1][1], s_g1[w1][2], s_g1[w1][3], s_g1[w1][4]);
                sh_flag = 0;
            } else sh_flag = 1;
        }
        __syncthreads();
        if (sh_flag) {
            // lazy masked sweep: argmax(y_pre * unact), jnp multiply semantics
            float mv2 = -INFINITY; int mi2 = 0;
#pragma unroll
            for (int j = 0; j < YTOT/NT; ++j) {
                const int idx = j*NT + tid;
                const unsigned wb = young[idx >> 5];
                const float m = yp[idx] * (((wb >> (tid & 31)) & 1u) ? 1.0f : 0.0f);
                if (m > mv2) { mv2 = m; mi2 = idx; }
            }
            for (int off = 32; off; off >>= 1) {
                float a = __shfl_down(mv2, off, 64); int b = __shfl_down(mi2, off, 64);
                amax_combine(mv2, mi2, a, b);
            }
            if (lane == 0) {
                s_v2[wv] = mv2; s_i2[wv] = mi2;
                s_g2[wv][0] = thr_in[mi2]; s_g2[wv][1] = age_y_in[mi2];
                s_g2[wv][2] = valz[mi2];   s_g2[wv][3] = nz2[mi2];
                s_g2[wv][4] = y2zrow[mi2];
            }
            __syncthreads();
            if (tid == 0) {
                float av = -INFINITY; int alt = 0x7fffffff; int w2 = 0;
                for (int w = 0; w < NWAVE; ++w) {
                    const float v = s_v2[w]; const int ii = s_i2[w];
                    if (v > av || (v == av && ii < alt)) { av = v; alt = ii; w2 = w; }
                }
                if (cnt > 0)
                    CAND_UPDATE(alt, s_g2[w2][0], s_g2[w2][1], s_g2[w2][2], s_g2[w2][3], s_g2[w2][4]);
                else
                    CAND_UPDATE(i0,  s_g1[w1][0], s_g1[w1][1], s_g1[w1][2], s_g1[w1][3], s_g1[w1][4]);
            }
            __syncthreads();
        }
    }

    // ---- Final: argmax over cA * activated-flag, output column, count
    {
        float bv = -INFINITY; int bi = 0;
#pragma unroll
        for (int j = 0; j < YTOT/NT; ++j) {
            const int idx = j*NT + tid;
            const unsigned wb = young[idx >> 5];
            const float flag = ((wb >> (tid & 31)) & 1u) ? 0.0f : 1.0f;
            const float v = cA[idx] * flag;
            if (v > bv) { bv = v; bi = idx; }
        }
        for (int off = 32; off; off >>= 1) {
            float a = __shfl_down(bv, off, 64); int b = __shfl_down(bi, off, 64);
            amax_combine(bv, bi, a, b);
        }
        if (lane == 0) { s_v1[wv] = bv; s_i1[wv] = bi; s_g1[wv][4] = y2zrow[bi]; }
    }
    __syncthreads();
    if (tid == 0) {
        float v = -INFINITY; int i = 0x7fffffff; int wf = 0;
        for (int w = 0; w < NWAVE; ++w) {
            if (s_v1[w] > v || (s_v1[w] == v && s_i1[w] < i)) { v = s_v1[w]; i = s_i1[w]; wf = w; }
        }
        sh_winf = i;
        sh_actn = (float)YTOT - (float)cnt;
        const float L = fmaxf(sqrtf(beta*beta*N0sq + 2.f*beta*Aacc + Bacc), EPSN);
        float g = 0.f, v0wf = s_g1[wf][4];
        for (int k = 0; k < ym_n; ++k) if (ym_idx[k] == i) { g = ym_g[k]; v0wf = ym_v0[k]; break; }
        sh_outz = (beta*v0wf + g) / L;
    }
    __syncthreads();
    if (tid < Z) {
        float o;
        if (tid == zv) o = sh_outz;
        else o = y2z[(size_t)tid * (size_t)Y + sh_winf] / fmaxf(sqrtf(nry[tid]), EPSN);
        out[tid] = o;
    }
    if (tid == 0) out[Z] = sh_actn;
}

extern "C" void kernel_launch(void* const* d_in, const int* in_sizes, int n_in,
                              void* d_out, int out_size, void* d_ws, size_t ws_size,
                              hipStream_t stream) {
    const float* x    = (const float*)d_in[0];
    const int*   z    = (const int*)d_in[1];
    const int*   pit  = (const int*)d_in[2];
    const float* x2y  = (const float*)d_in[3];
    const float* z2y  = (const float*)d_in[4];
    const float* y2z  = (const float*)d_in[5];
    const float* agey = (const float*)d_in[6];
    const float* agez = (const float*)d_in[7];
    const float* thr  = (const float*)d_in[8];
    const int X = in_sizes[0];   // 4096
    const int Y = in_sizes[6];   // 16384
    const int Z = in_sizes[7];   // 100

    float* ws   = (float*)d_ws;
    float* dotx = ws;
    float* nw2  = ws + Y;
    float* valz = ws + 2*(size_t)Y;
    float* nz2  = ws + 3*(size_t)Y;
    float* nry  = ws + 4*(size_t)Y;
    float* out  = (float*)d_out;

    const int grid_prep = Y/4 + Z + Y;   // z2y blocks + y2z blocks + x2y blocks
    hipLaunchKernelGGL(k_prep, dim3(grid_prep), dim3(256), 0, stream,
                       x2y, z2y, y2z, z, x, dotx, nw2, valz, nz2, nry, X, Y, Z);
    hipLaunchKernelGGL(k_train, dim3(1), dim3(NT), 0, stream,
                       x, z, pit, y2z, agey, agez, thr,
                       dotx, nw2, valz, nz2, nry, out, X, Y, Z);
}

// Round 4
// 88.459 us; speedup vs baseline: 3.1712x; 1.1701x over previous
//
#include <hip/hip_runtime.h>
#include <cmath>

#define EPSN 1e-12f
#define CHUNK 128
#define NCH 128          // Y / CHUNK for Y=16384
#define NTL 128          // threads in k_loop / k_combine
#define MAPCAP 32

__device__ __forceinline__ void amax_combine(float& v, int& i, float ov, int oi) {
    // jnp.argmax semantics: max value, first (lowest) index on ties
    if (ov > v || (ov == v && oi < i)) { v = ov; i = oi; }
}
__device__ __forceinline__ void wave_amax(float& v, int& i) {
    for (int off = 32; off; off >>= 1) {
        float a = __shfl_down(v, off, 64);
        int b = __shfl_down(i, off, 64);
        amax_combine(v, i, a, b);
    }
}

// ---------------------------------------------------------------------------
// k_prep: z2y row stats (blocks [0,NBZ)), y2z row norms ([NBZ,NBZ+Z)),
// x2y dot+norm2 ([NBZ+Z, NBZ+Z+Y)), ||x||^2 + cnt=0 (last block).
__global__ __launch_bounds__(256) void k_prep(
    const float* __restrict__ x2y, const float* __restrict__ z2y,
    const float* __restrict__ y2z, const int* __restrict__ zptr,
    const float* __restrict__ x,
    float* __restrict__ dotx, float* __restrict__ nw2,
    float* __restrict__ valz, float* __restrict__ nz2,
    float* __restrict__ nry, float* __restrict__ xn2, int* __restrict__ cnti,
    int X, int Y, int Z)
{
    const int bid = blockIdx.x;
    const int NBZ = Y / 4;
    const int tid = threadIdx.x;
    const int lane = tid & 63, wv = tid >> 6;
    if (bid < NBZ) {
        const int zv = zptr[0];
        const int row = bid * 4 + wv;
        const float* r = z2y + (size_t)row * Z;
        float q = 0.f, v = 0.f;
        for (int j = lane; j < Z; j += 64) {
            float e = r[j];
            q += e * e;
            if (j == zv) v = e;
        }
        for (int off = 32; off; off >>= 1) {
            q += __shfl_down(q, off, 64);
            v += __shfl_down(v, off, 64);
        }
        if (lane == 0) { nz2[row] = q; valz[row] = v; }
    } else if (bid < NBZ + Z) {
        const int row = bid - NBZ;
        const float4* r4 = (const float4*)(y2z + (size_t)row * Y);
        float q = 0.f;
        for (int i = tid; i < (Y >> 2); i += 256) {
            float4 w = r4[i];
            q += w.x*w.x + w.y*w.y + w.z*w.z + w.w*w.w;
        }
        for (int off = 32; off; off >>= 1) q += __shfl_down(q, off, 64);
        __shared__ float sq[4];
        if (lane == 0) sq[wv] = q;
        __syncthreads();
        if (tid == 0) nry[row] = sq[0] + sq[1] + sq[2] + sq[3];
    } else if (bid < NBZ + Z + Y) {
        const int row = bid - NBZ - Z;
        const float4* w4 = (const float4*)(x2y + (size_t)row * X);
        const float4* x4 = (const float4*)x;
        float d = 0.f, q = 0.f;
        for (int i = tid; i < (X >> 2); i += 256) {
            float4 w = w4[i]; float4 xx = x4[i];
            d += w.x*xx.x + w.y*xx.y + w.z*xx.z + w.w*xx.w;
            q += w.x*w.x + w.y*w.y + w.z*w.z + w.w*w.w;
        }
        for (int off = 32; off; off >>= 1) {
            d += __shfl_down(d, off, 64);
            q += __shfl_down(q, off, 64);
        }
        __shared__ float sd[4], sq2[4];
        if (lane == 0) { sd[wv] = d; sq2[wv] = q; }
        __syncthreads();
        if (tid == 0) {
            dotx[row] = sd[0] + sd[1] + sd[2] + sd[3];
            nw2[row]  = sq2[0] + sq2[1] + sq2[2] + sq2[3];
        }
    } else {
        // ||x||^2 and init young-counter
        const float4* x4 = (const float4*)x;
        float q = 0.f;
        for (int i = tid; i < (X >> 2); i += 256) {
            float4 xx = x4[i];
            q += xx.x*xx.x + xx.y*xx.y + xx.z*xx.z + xx.w*xx.w;
        }
        for (int off = 32; off; off >>= 1) q += __shfl_down(q, off, 64);
        __shared__ float sq3[4];
        if (lane == 0) sq3[wv] = q;
        __syncthreads();
        if (tid == 0) { xn2[0] = sq3[0]+sq3[1]+sq3[2]+sq3[3]; cnti[0] = 0; }
    }
}

// ---------------------------------------------------------------------------
// k_combine: grid-wide per-neuron math + per-chunk argmax stats. 128 blk x 128.
__global__ __launch_bounds__(NTL) void k_combine(
    const float* __restrict__ age_y_in,
    const float* __restrict__ dotx, const float* __restrict__ nw2,
    const float* __restrict__ valz, const float* __restrict__ nz2,
    const float* __restrict__ xn2,
    float* __restrict__ yp_ws, float* __restrict__ cA_ws,
    float* __restrict__ chv, int* __restrict__ chi,
    float* __restrict__ chcv, int* __restrict__ chci,
    int* __restrict__ cnti)
{
    const int b = blockIdx.x, t = threadIdx.x;
    const int e = b * CHUNK + t;
    const int lane = t & 63, wv = t >> 6;
    const float xn = fmaxf(sqrtf(xn2[0]), EPSN);
    const float c = dotx[e] / (fmaxf(sqrtf(nw2[e]), EPSN) * xn);
    const float s = valz[e] / fmaxf(sqrtf(nz2[e]), EPSN);
    const float ypv = 0.5f * (c + s);
    const float agev = age_y_in[e];
    const int young = agev < 1.0f;
    cA_ws[e] = c;
    yp_ws[e] = ypv;
    float v1 = ypv; int i1 = e;
    float v2 = c * (young ? 0.0f : 1.0f); int i2 = e;   // jnp multiply-mask (±0)
    int yc = young;
    wave_amax(v1, i1);
    wave_amax(v2, i2);
    for (int off = 32; off; off >>= 1) yc += __shfl_down(yc, off, 64);
    __shared__ float s1v[2]; __shared__ int s1i[2];
    __shared__ float s2v[2]; __shared__ int s2i[2];
    __shared__ int syc[2];
    if (lane == 0) { s1v[wv] = v1; s1i[wv] = i1; s2v[wv] = v2; s2i[wv] = i2; syc[wv] = yc; }
    __syncthreads();
    if (t == 0) {
        float a = s1v[0]; int ai = s1i[0];
        amax_combine(a, ai, s1v[1], s1i[1]);
        float bmv = s2v[0]; int bmi = s2i[0];
        amax_combine(bmv, bmi, s2v[1], s2i[1]);
        chv[b] = a; chi[b] = ai; chcv[b] = bmv; chci[b] = bmi;
        atomicAdd(cnti, syc[0] + syc[1]);
    }
}

// ---------------------------------------------------------------------------
// Thread-0 winner update. All state in LDS maps / thread-0 regs. Gx are the
// candidate's ORIGINAL thr/age/valz/nz2/y2z-elem/cA (wm map overrides inside).
#define UPD(WIN, Gthr, Gage, Gvz, Gnz, Gy2z, Gc) do { \
    const int w_ = (WIN); \
    float age_o = (Gage), thr_o = (Gthr), c_o = (Gc); \
    float s_o = (Gvz) / fmaxf(sqrtf((Gnz)), EPSN); \
    int e_ = -1; \
    const int wmn_ = sh_wmn; \
    for (int k_ = 0; k_ < wmn_; ++k_) if (wm_idx[k_] == w_) { \
        age_o = wm_age[k_]; thr_o = wm_thr[k_]; s_o = wm_s[k_]; c_o = wm_c[k_]; e_ = k_; break; } \
    const float lr_ = 1.f/(age_o+1.f), om_ = 1.f-lr_; \
    const float cn_ = (om_*c_o+lr_)/fmaxf(sqrtf(om_*om_+lr_*lr_+2.f*lr_*om_*c_o), EPSN); \
    const float sn_ = (om_*s_o+lr_)/fmaxf(sqrtf(om_*om_+lr_*lr_+2.f*lr_*om_*s_o), EPSN); \
    if (e_ < 0) { e_ = wmn_; wm_idx[e_] = w_; sh_wmn = wmn_ + 1; } \
    wm_age[e_] = age_o + 1.f; wm_thr[e_] = lr_*r0 + om_*thr_o; \
    wm_s[e_] = sn_; wm_c[e_] = cn_; wm_yp[e_] = 0.5f*(cn_+sn_); \
    if (age_o < 1.f && age_o + 1.f >= 1.f) cnt--; \
    { const int cw_ = w_ >> 7; \
      float vv_ = chcv_l[cw_]; int ii_ = chci_l[cw_]; \
      amax_combine(vv_, ii_, cn_, w_); \
      chcv_l[cw_] = vv_; chci_l[cw_] = ii_; } \
    const float L_ = fmaxf(sqrtf(beta*beta*N0sq + 2.f*beta*Aacc + Bacc), EPSN); \
    beta /= L_; Aacc /= L_; Bacc /= (L_*L_); \
    for (int k_ = 0; k_ < ym_n; ++k_) ym_g[k_] /= L_; \
    const float zlr_ = 1.f/(agez+1.f), oz_ = 1.f-zlr_; \
    beta *= oz_; Aacc *= oz_; Bacc *= oz_*oz_; \
    for (int k_ = 0; k_ < ym_n; ++k_) ym_g[k_] *= oz_; \
    int q_ = 0; for (; q_ < ym_n; ++q_) if (ym_idx[q_] == w_) break; \
    if (q_ == ym_n) { ym_idx[q_] = w_; ym_g[q_] = 0.f; ym_v0[q_] = (Gy2z); ym_n++; } \
    const float gold_ = ym_g[q_]; \
    Bacc += 2.f*zlr_*gold_ + zlr_*zlr_; \
    Aacc += zlr_*ym_v0[q_]; \
    ym_g[q_] = gold_ + zlr_; \
    agez += 1.f; \
    sh_win = w_; \
} while (0)

__global__ __launch_bounds__(NTL) void k_loop(
    const int* __restrict__ zptr, const int* __restrict__ pitem,
    const float* __restrict__ y2z,
    const float* __restrict__ age_y_in, const float* __restrict__ age_z_in,
    const float* __restrict__ thr_in,
    const float* __restrict__ valz, const float* __restrict__ nz2,
    const float* __restrict__ nry,
    const float* __restrict__ yp_ws, const float* __restrict__ cA_ws,
    const float* __restrict__ chv, const int* __restrict__ chi,
    const float* __restrict__ chcv, const int* __restrict__ chci,
    const int* __restrict__ cnti,
    float* __restrict__ out, int Y, int Z)
{
    __shared__ float chv_l[NCH]; __shared__ int chi_l[NCH];
    __shared__ float chcv_l[NCH]; __shared__ int chci_l[NCH];
    __shared__ float pthr[NCH], page[NCH], pvz[NCH], pnz[NCH], pyz[NCH], pca[NCH];
    __shared__ float rv[2]; __shared__ int ri[2];
    __shared__ int   wm_idx[MAPCAP];
    __shared__ float wm_age[MAPCAP], wm_thr[MAPCAP], wm_s[MAPCAP], wm_c[MAPCAP], wm_yp[MAPCAP];
    __shared__ int   ym_idx[MAPCAP];
    __shared__ float ym_g[MAPCAP], ym_v0[MAPCAP];
    __shared__ float sh_outz, sh_actn;
    __shared__ int sh_win, sh_winf, sh_flag, sh_wmn;

    const int tid = threadIdx.x, lane = tid & 63, wv = tid >> 6;
    const int zv = zptr[0];
    const float* __restrict__ y2zrow = y2z + (size_t)zv * Y;

    // load chunk stats into LDS
    chv_l[tid]  = chv[tid];  chi_l[tid]  = chi[tid];
    chcv_l[tid] = chcv[tid]; chci_l[tid] = chci[tid];
    if (tid == 0) sh_wmn = 0;
    __syncthreads();

    // thread-0 persistent scalars
    int cnt = 0, ym_n = 0;
    float beta = 1.f, Aacc = 0.f, Bacc = 0.f, N0sq = 0.f, agez = 0.f;
    float r0 = 0.f; int i0 = 0;
    if (tid == 0) { cnt = cnti[0]; N0sq = nry[zv]; agez = age_z_in[zv]; }

    const int PI = pitem[0];
    for (int t = 0; t < PI; ++t) {
        // (a) parallel prefetch of every chunk-candidate's original state
        const int ci = chi_l[tid];
        pthr[tid] = thr_in[ci];  page[tid] = age_y_in[ci];
        pvz[tid]  = valz[ci];    pnz[tid]  = nz2[ci];
        pyz[tid]  = y2zrow[ci];  pca[tid]  = cA_ws[ci];
        // (b) argmax over 128 chunk maxima
        float v = chv_l[tid]; int i = chi_l[tid];
        wave_amax(v, i);
        if (lane == 0) { rv[wv] = v; ri[wv] = i; }
        __syncthreads();
        if (tid == 0) {
            r0 = rv[0]; i0 = ri[0];
            amax_combine(r0, i0, rv[1], ri[1]);
            const int ts = i0 >> 7;     // candidate's owning chunk == prefetch slot
            float age0 = page[ts], thr0 = pthr[ts];
            for (int k = 0; k < sh_wmn; ++k)
                if (wm_idx[k] == i0) { age0 = wm_age[k]; thr0 = wm_thr[k]; break; }
            const bool keep = (r0 > thr0) || (age0 < 1.f);
            if (keep) {
                UPD(i0, pthr[ts], page[ts], pvz[ts], pnz[ts], pyz[ts], pca[ts]);
                sh_flag = 0;
            } else sh_flag = 1;
        }
        __syncthreads();
        if (sh_flag) {   // rare: full masked sweep with wm overrides
            float mv = -INFINITY; int mi = 0;
            const int wmn = sh_wmn;
            for (int j = 0; j < Y / NTL; ++j) {
                const int e = j * NTL + tid;
                float vv = yp_ws[e];
                float ag = age_y_in[e];
                for (int k = 0; k < wmn; ++k)
                    if (wm_idx[k] == e) { vv = wm_yp[k]; ag = wm_age[k]; break; }
                const float m = vv * (ag < 1.f ? 1.f : 0.f);   // jnp ±0 mask
                if (m > mv) { mv = m; mi = e; }
            }
            wave_amax(mv, mi);
            if (lane == 0) { rv[wv] = mv; ri[wv] = mi; }
            __syncthreads();
            if (tid == 0) {
                float av = rv[0]; int alt = ri[0];
                amax_combine(av, alt, rv[1], ri[1]);
                if (cnt > 0) {
                    const float gthr = thr_in[alt], gage = age_y_in[alt];
                    const float gvz = valz[alt],  gnz = nz2[alt];
                    const float gy  = y2zrow[alt], gc = cA_ws[alt];
                    UPD(alt, gthr, gage, gvz, gnz, gy, gc);
                } else {
                    const int ts = i0 >> 7;
                    UPD(i0, pthr[ts], page[ts], pvz[ts], pnz[ts], pyz[ts], pca[ts]);
                }
            }
            __syncthreads();
        }
        // (c) rescan winner's 128-element chunk (512 B, wm-overridden)
        const int cw = sh_win >> 7;
        {
            const int e = cw * CHUNK + tid;
            float vv = yp_ws[e];
            const int wmn = sh_wmn;
            for (int k = 0; k < wmn; ++k) if (wm_idx[k] == e) { vv = wm_yp[k]; break; }
            int ii = e;
            wave_amax(vv, ii);
            if (lane == 0) { rv[wv] = vv; ri[wv] = ii; }
        }
        __syncthreads();
        if (tid == 0) {
            float vv = rv[0]; int ii = ri[0];
            amax_combine(vv, ii, rv[1], ri[1]);
            chv_l[cw] = vv; chi_l[cw] = ii;
        }
        __syncthreads();
    }

    // ---- Final: argmax over maintained cA*flag chunk maxima
    {
        float v = chcv_l[tid]; int i = chci_l[tid];
        wave_amax(v, i);
        if (lane == 0) { rv[wv] = v; ri[wv] = i; }
    }
    __syncthreads();
    if (tid == 0) {
        float v = rv[0]; int i = ri[0];
        amax_combine(v, i, rv[1], ri[1]);
        sh_winf = i;
        sh_actn = (float)Y - (float)cnt;
        const float L = fmaxf(sqrtf(beta*beta*N0sq + 2.f*beta*Aacc + Bacc), EPSN);
        float g = 0.f, v0wf = 0.f; bool found = false;
        for (int k = 0; k < ym_n; ++k)
            if (ym_idx[k] == i) { g = ym_g[k]; v0wf = ym_v0[k]; found = true; break; }
        if (!found) v0wf = y2zrow[i];
        sh_outz = (beta * v0wf + g) / L;
    }
    __syncthreads();
    if (tid < Z) {
        float o = (tid == zv) ? sh_outz
                : y2z[(size_t)tid * (size_t)Y + sh_winf] / fmaxf(sqrtf(nry[tid]), EPSN);
        out[tid] = o;
    }
    if (tid == 0) out[Z] = sh_actn;
}

extern "C" void kernel_launch(void* const* d_in, const int* in_sizes, int n_in,
                              void* d_out, int out_size, void* d_ws, size_t ws_size,
                              hipStream_t stream) {
    const float* x    = (const float*)d_in[0];
    const int*   z    = (const int*)d_in[1];
    const int*   pit  = (const int*)d_in[2];
    const float* x2y  = (const float*)d_in[3];
    const float* z2y  = (const float*)d_in[4];
    const float* y2z  = (const float*)d_in[5];
    const float* agey = (const float*)d_in[6];
    const float* agez = (const float*)d_in[7];
    const float* thr  = (const float*)d_in[8];
    const int X = in_sizes[0];   // 4096
    const int Y = in_sizes[6];   // 16384
    const int Z = in_sizes[7];   // 100

    float* ws = (float*)d_ws;
    float* dotx = ws;                       // Y
    float* nw2  = ws + (size_t)Y;           // Y
    float* valz = ws + 2*(size_t)Y;         // Y
    float* nz2  = ws + 3*(size_t)Y;         // Y
    float* nry  = ws + 4*(size_t)Y;         // Z (pad to 128)
    float* xn2  = ws + 4*(size_t)Y + 128;   // 1
    int*   cnti = (int*)(ws + 4*(size_t)Y + 129);
    float* ypw  = ws + 4*(size_t)Y + 256;   // Y
    float* cAw  = ws + 5*(size_t)Y + 256;   // Y
    float* chv  = ws + 6*(size_t)Y + 256;   // NCH
    int*   chi  = (int*)(ws + 6*(size_t)Y + 384);
    float* chcv = ws + 6*(size_t)Y + 512;
    int*   chci = (int*)(ws + 6*(size_t)Y + 640);
    float* out  = (float*)d_out;

    const int NBZ = Y / 4;
    const int grid_prep = NBZ + Z + Y + 1;
    hipLaunchKernelGGL(k_prep, dim3(grid_prep), dim3(256), 0, stream,
                       x2y, z2y, y2z, z, x, dotx, nw2, valz, nz2, nry, xn2, cnti, X, Y, Z);
    hipLaunchKernelGGL(k_combine, dim3(Y / CHUNK), dim3(NTL), 0, stream,
                       agey, dotx, nw2, valz, nz2, xn2, ypw, cAw, chv, chi, chcv, chci, cnti);
    hipLaunchKernelGGL(k_loop, dim3(1), dim3(NTL), 0, stream,
                       z, pit, y2z, agey, agez, thr, valz, nz2, nry,
                       ypw, cAw, chv, chi, chcv, chci, cnti, out, Y, Z);
}

// Round 5
// 85.419 us; speedup vs baseline: 3.2840x; 1.0356x over previous
//
#include <hip/hip_runtime.h>
#include <cmath>

#define EPSN 1e-12f
#define CHUNK 128
#define NCH 128          // Y / CHUNK for Y=16384
#define NTL 128          // threads in k_loop / k_combine
#define MAPCAP 32

__device__ __forceinline__ void amax_combine(float& v, int& i, float ov, int oi) {
    // jnp.argmax semantics: max value, first (lowest) index on ties
    if (ov > v || (ov == v && oi < i)) { v = ov; i = oi; }
}
__device__ __forceinline__ void wave_amax(float& v, int& i) {
    for (int off = 32; off; off >>= 1) {
        float a = __shfl_down(v, off, 64);
        int b = __shfl_down(i, off, 64);
        amax_combine(v, i, a, b);
    }
}

// ---------------------------------------------------------------------------
// k_prep: z2y row stats (blocks [0,NBZ)), y2z row norms ([NBZ,NBZ+Z)),
// x2y dot+norm2 ([NBZ+Z, NBZ+Z+Y)), ||x||^2 + cnt=0 (last block).
__global__ __launch_bounds__(256) void k_prep(
    const float* __restrict__ x2y, const float* __restrict__ z2y,
    const float* __restrict__ y2z, const int* __restrict__ zptr,
    const float* __restrict__ x,
    float* __restrict__ dotx, float* __restrict__ nw2,
    float* __restrict__ valz, float* __restrict__ nz2,
    float* __restrict__ nry, float* __restrict__ xn2, int* __restrict__ cnti,
    int X, int Y, int Z)
{
    const int bid = blockIdx.x;
    const int NBZ = Y / 4;
    const int tid = threadIdx.x;
    const int lane = tid & 63, wv = tid >> 6;
    if (bid < NBZ) {
        const int zv = zptr[0];
        const int row = bid * 4 + wv;
        const float* r = z2y + (size_t)row * Z;
        float q = 0.f, v = 0.f;
        for (int j = lane; j < Z; j += 64) {
            float e = r[j];
            q += e * e;
            if (j == zv) v = e;
        }
        for (int off = 32; off; off >>= 1) {
            q += __shfl_down(q, off, 64);
            v += __shfl_down(v, off, 64);
        }
        if (lane == 0) { nz2[row] = q; valz[row] = v; }
    } else if (bid < NBZ + Z) {
        const int row = bid - NBZ;
        const float4* r4 = (const float4*)(y2z + (size_t)row * Y);
        float q = 0.f;
        for (int i = tid; i < (Y >> 2); i += 256) {
            float4 w = r4[i];
            q += w.x*w.x + w.y*w.y + w.z*w.z + w.w*w.w;
        }
        for (int off = 32; off; off >>= 1) q += __shfl_down(q, off, 64);
        __shared__ float sq[4];
        if (lane == 0) sq[wv] = q;
        __syncthreads();
        if (tid == 0) nry[row] = sq[0] + sq[1] + sq[2] + sq[3];
    } else if (bid < NBZ + Z + Y) {
        const int row = bid - NBZ - Z;
        const float4* w4 = (const float4*)(x2y + (size_t)row * X);
        const float4* x4 = (const float4*)x;
        float d = 0.f, q = 0.f;
        for (int i = tid; i < (X >> 2); i += 256) {
            float4 w = w4[i]; float4 xx = x4[i];
            d += w.x*xx.x + w.y*xx.y + w.z*xx.z + w.w*xx.w;
            q += w.x*w.x + w.y*w.y + w.z*w.z + w.w*w.w;
        }
        for (int off = 32; off; off >>= 1) {
            d += __shfl_down(d, off, 64);
            q += __shfl_down(q, off, 64);
        }
        __shared__ float sd[4], sq2[4];
        if (lane == 0) { sd[wv] = d; sq2[wv] = q; }
        __syncthreads();
        if (tid == 0) {
            dotx[row] = sd[0] + sd[1] + sd[2] + sd[3];
            nw2[row]  = sq2[0] + sq2[1] + sq2[2] + sq2[3];
        }
    } else {
        // ||x||^2 and init young-counter
        const float4* x4 = (const float4*)x;
        float q = 0.f;
        for (int i = tid; i < (X >> 2); i += 256) {
            float4 xx = x4[i];
            q += xx.x*xx.x + xx.y*xx.y + xx.z*xx.z + xx.w*xx.w;
        }
        for (int off = 32; off; off >>= 1) q += __shfl_down(q, off, 64);
        __shared__ float sq3[4];
        if (lane == 0) sq3[wv] = q;
        __syncthreads();
        if (tid == 0) { xn2[0] = sq3[0]+sq3[1]+sq3[2]+sq3[3]; cnti[0] = 0; }
    }
}

// ---------------------------------------------------------------------------
// k_combine: grid-wide per-neuron math + per-chunk argmax stats. 128 blk x 128.
__global__ __launch_bounds__(NTL) void k_combine(
    const float* __restrict__ age_y_in,
    const float* __restrict__ dotx, const float* __restrict__ nw2,
    const float* __restrict__ valz, const float* __restrict__ nz2,
    const float* __restrict__ xn2,
    float* __restrict__ yp_ws, float* __restrict__ cA_ws,
    float* __restrict__ chv, int* __restrict__ chi,
    float* __restrict__ chcv, int* __restrict__ chci,
    int* __restrict__ cnti)
{
    const int b = blockIdx.x, t = threadIdx.x;
    const int e = b * CHUNK + t;
    const int lane = t & 63, wv = t >> 6;
    const float xn = fmaxf(sqrtf(xn2[0]), EPSN);
    const float c = dotx[e] / (fmaxf(sqrtf(nw2[e]), EPSN) * xn);
    const float s = valz[e] / fmaxf(sqrtf(nz2[e]), EPSN);
    const float ypv = 0.5f * (c + s);
    const float agev = age_y_in[e];
    const int young = agev < 1.0f;
    cA_ws[e] = c;
    yp_ws[e] = ypv;
    float v1 = ypv; int i1 = e;
    float v2 = c * (young ? 0.0f : 1.0f); int i2 = e;   // jnp multiply-mask (±0)
    int yc = young;
    wave_amax(v1, i1);
    wave_amax(v2, i2);
    for (int off = 32; off; off >>= 1) yc += __shfl_down(yc, off, 64);
    __shared__ float s1v[2]; __shared__ int s1i[2];
    __shared__ float s2v[2]; __shared__ int s2i[2];
    __shared__ int syc[2];
    if (lane == 0) { s1v[wv] = v1; s1i[wv] = i1; s2v[wv] = v2; s2i[wv] = i2; syc[wv] = yc; }
    __syncthreads();
    if (t == 0) {
        float a = s1v[0]; int ai = s1i[0];
        amax_combine(a, ai, s1v[1], s1i[1]);
        float bmv = s2v[0]; int bmi = s2i[0];
        amax_combine(bmv, bmi, s2v[1], s2i[1]);
        chv[b] = a; chi[b] = ai; chcv[b] = bmv; chci[b] = bmi;
        atomicAdd(cnti, syc[0] + syc[1]);
    }
}

// ---------------------------------------------------------------------------
// Thread-0 winner update. All state in LDS maps / thread-0 regs. Gx are the
// candidate's ORIGINAL thr/age/valz/nz2/y2z-elem/cA (wm map overrides inside).
#define UPD(WIN, Gthr, Gage, Gvz, Gnz, Gy2z, Gc) do { \
    const int w_ = (WIN); \
    float age_o = (Gage), thr_o = (Gthr), c_o = (Gc); \
    float s_o = (Gvz) / fmaxf(sqrtf((Gnz)), EPSN); \
    int e_ = -1; \
    const int wmn_ = sh_wmn; \
    for (int k_ = 0; k_ < wmn_; ++k_) if (wm_idx[k_] == w_) { \
        age_o = wm_age[k_]; thr_o = wm_thr[k_]; s_o = wm_s[k_]; c_o = wm_c[k_]; e_ = k_; break; } \
    const float lr_ = 1.f/(age_o+1.f), om_ = 1.f-lr_; \
    const float cn_ = (om_*c_o+lr_)/fmaxf(sqrtf(om_*om_+lr_*lr_+2.f*lr_*om_*c_o), EPSN); \
    const float sn_ = (om_*s_o+lr_)/fmaxf(sqrtf(om_*om_+lr_*lr_+2.f*lr_*om_*s_o), EPSN); \
    if (e_ < 0) { e_ = wmn_; wm_idx[e_] = w_; sh_wmn = wmn_ + 1; } \
    wm_age[e_] = age_o + 1.f; wm_thr[e_] = lr_*r0 + om_*thr_o; \
    wm_s[e_] = sn_; wm_c[e_] = cn_; wm_yp[e_] = 0.5f*(cn_+sn_); \
    if (age_o < 1.f && age_o + 1.f >= 1.f) cnt--; \
    { const int cw_ = w_ >> 7; \
      float vv_ = chcv_l[cw_]; int ii_ = chci_l[cw_]; \
      amax_combine(vv_, ii_, cn_, w_); \
      chcv_l[cw_] = vv_; chci_l[cw_] = ii_; } \
    const float L_ = fmaxf(sqrtf(beta*beta*N0sq + 2.f*beta*Aacc + Bacc), EPSN); \
    beta /= L_; Aacc /= L_; Bacc /= (L_*L_); \
    for (int k_ = 0; k_ < ym_n; ++k_) ym_g[k_] /= L_; \
    const float zlr_ = 1.f/(agez+1.f), oz_ = 1.f-zlr_; \
    beta *= oz_; Aacc *= oz_; Bacc *= oz_*oz_; \
    for (int k_ = 0; k_ < ym_n; ++k_) ym_g[k_] *= oz_; \
    int q_ = 0; for (; q_ < ym_n; ++q_) if (ym_idx[q_] == w_) break; \
    if (q_ == ym_n) { ym_idx[q_] = w_; ym_g[q_] = 0.f; ym_v0[q_] = (Gy2z); ym_n++; } \
    const float gold_ = ym_g[q_]; \
    Bacc += 2.f*zlr_*gold_ + zlr_*zlr_; \
    Aacc += zlr_*ym_v0[q_]; \
    ym_g[q_] = gold_ + zlr_; \
    agez += 1.f; \
    sh_win = w_; \
} while (0)

__global__ __launch_bounds__(NTL) void k_loop(
    const int* __restrict__ zptr, const int* __restrict__ pitem,
    const float* __restrict__ y2z,
    const float* __restrict__ age_y_in, const float* __restrict__ age_z_in,
    const float* __restrict__ thr_in,
    const float* __restrict__ valz, const float* __restrict__ nz2,
    const float* __restrict__ nry,
    const float* __restrict__ yp_ws, const float* __restrict__ cA_ws,
    const float* __restrict__ chv, const int* __restrict__ chi,
    const float* __restrict__ chcv, const int* __restrict__ chci,
    const int* __restrict__ cnti,
    float* __restrict__ out, int Y, int Z)
{
    __shared__ float chv_l[NCH]; __shared__ int chi_l[NCH];
    __shared__ float chcv_l[NCH]; __shared__ int chci_l[NCH];
    __shared__ float pthr[NCH], page[NCH], pvz[NCH], pnz[NCH], pyz[NCH], pca[NCH];
    __shared__ float rv[2]; __shared__ int ri[2];
    __shared__ int   wm_idx[MAPCAP];
    __shared__ float wm_age[MAPCAP], wm_thr[MAPCAP], wm_s[MAPCAP], wm_c[MAPCAP], wm_yp[MAPCAP];
    __shared__ int   ym_idx[MAPCAP];
    __shared__ float ym_g[MAPCAP], ym_v0[MAPCAP];
    __shared__ float sh_outz, sh_actn;
    __shared__ int sh_win, sh_winf, sh_flag, sh_wmn;

    const int tid = threadIdx.x, lane = tid & 63, wv = tid >> 6;
    const int zv = zptr[0];
    const float* __restrict__ y2zrow = y2z + (size_t)zv * Y;

    // load chunk stats into LDS
    chv_l[tid]  = chv[tid];  chi_l[tid]  = chi[tid];
    chcv_l[tid] = chcv[tid]; chci_l[tid] = chci[tid];
    if (tid == 0) sh_wmn = 0;
    __syncthreads();

    // ONE-TIME parallel prefetch of every chunk-candidate's original state.
    // Per iteration only the winner chunk's candidate can change; that single
    // slot is refilled at iteration end by 6 threads.
    {
        const int ci = chi_l[tid];
        pthr[tid] = thr_in[ci];  page[tid] = age_y_in[ci];
        pvz[tid]  = valz[ci];    pnz[tid]  = nz2[ci];
        pyz[tid]  = y2zrow[ci];  pca[tid]  = cA_ws[ci];
    }

    // thread-0 persistent scalars
    int cnt = 0, ym_n = 0;
    float beta = 1.f, Aacc = 0.f, Bacc = 0.f, N0sq = 0.f, agez = 0.f;
    float r0 = 0.f; int i0 = 0;
    if (tid == 0) { cnt = cnti[0]; N0sq = nry[zv]; agez = age_z_in[zv]; }

    const int PI = pitem[0];
    for (int t = 0; t < PI; ++t) {
        // (a) argmax over 128 chunk maxima (LDS)
        float v = chv_l[tid]; int i = chi_l[tid];
        wave_amax(v, i);
        if (lane == 0) { rv[wv] = v; ri[wv] = i; }
        __syncthreads();   // B1: also drains prefetch/refill LDS writes
        if (tid == 0) {
            r0 = rv[0]; i0 = ri[0];
            amax_combine(r0, i0, rv[1], ri[1]);
            const int ts = i0 >> 7;     // candidate's owning chunk == prefetch slot
            float age0 = page[ts], thr0 = pthr[ts];
            for (int k = 0; k < sh_wmn; ++k)
                if (wm_idx[k] == i0) { age0 = wm_age[k]; thr0 = wm_thr[k]; break; }
            const bool keep = (r0 > thr0) || (age0 < 1.f);
            if (keep) {
                UPD(i0, pthr[ts], page[ts], pvz[ts], pnz[ts], pyz[ts], pca[ts]);
                sh_flag = 0;
            } else sh_flag = 1;
        }
        __syncthreads();   // B2
        if (sh_flag) {   // rare: full masked sweep with wm overrides
            float mv = -INFINITY; int mi = 0;
            const int wmn = sh_wmn;
            for (int j = 0; j < Y / NTL; ++j) {
                const int e = j * NTL + tid;
                float vv = yp_ws[e];
                float ag = age_y_in[e];
                for (int k = 0; k < wmn; ++k)
                    if (wm_idx[k] == e) { vv = wm_yp[k]; ag = wm_age[k]; break; }
                const float m = vv * (ag < 1.f ? 1.f : 0.f);   // jnp ±0 mask
                if (m > mv) { mv = m; mi = e; }
            }
            wave_amax(mv, mi);
            if (lane == 0) { rv[wv] = mv; ri[wv] = mi; }
            __syncthreads();
            if (tid == 0) {
                float av = rv[0]; int alt = ri[0];
                amax_combine(av, alt, rv[1], ri[1]);
                if (cnt > 0) {
                    const float gthr = thr_in[alt], gage = age_y_in[alt];
                    const float gvz = valz[alt],  gnz = nz2[alt];
                    const float gy  = y2zrow[alt], gc = cA_ws[alt];
                    UPD(alt, gthr, gage, gvz, gnz, gy, gc);
                } else {
                    const int ts = i0 >> 7;
                    UPD(i0, pthr[ts], page[ts], pvz[ts], pnz[ts], pyz[ts], pca[ts]);
                }
            }
            __syncthreads();
        }
        // (b) rescan winner's 128-element chunk (512 B, wm-overridden)
        const int cw = sh_win >> 7;
        {
            const int e = cw * CHUNK + tid;
            float vv = yp_ws[e];
            const int wmn = sh_wmn;
            for (int k = 0; k < wmn; ++k) if (wm_idx[k] == e) { vv = wm_yp[k]; break; }
            int ii = e;
            wave_amax(vv, ii);
            if (lane == 0) { rv[wv] = vv; ri[wv] = ii; }
        }
        __syncthreads();   // B3
        if (tid == 0) {
            float vv = rv[0]; int ii = ri[0];
            amax_combine(vv, ii, rv[1], ri[1]);
            chv_l[cw] = vv; chi_l[cw] = ii;
        }
        __syncthreads();   // B4
        // (c) refill ONLY the winner chunk's prefetch slot (new candidate)
        if (tid < 6) {
            const int nc = chi_l[cw];
            if      (tid == 0) pthr[cw] = thr_in[nc];
            else if (tid == 1) page[cw] = age_y_in[nc];
            else if (tid == 2) pvz[cw]  = valz[nc];
            else if (tid == 3) pnz[cw]  = nz2[nc];
            else if (tid == 4) pyz[cw]  = y2zrow[nc];
            else               pca[cw]  = cA_ws[nc];
        }
        // next iteration's B1 guarantees refill completion before use
    }

    // ---- Final: argmax over maintained cA*flag chunk maxima
    {
        float v = chcv_l[tid]; int i = chci_l[tid];
        wave_amax(v, i);
        if (lane == 0) { rv[wv] = v; ri[wv] = i; }
    }
    __syncthreads();
    if (tid == 0) {
        float v = rv[0]; int i = ri[0];
        amax_combine(v, i, rv[1], ri[1]);
        sh_winf = i;
        sh_actn = (float)Y - (float)cnt;
        const float L = fmaxf(sqrtf(beta*beta*N0sq + 2.f*beta*Aacc + Bacc), EPSN);
        float g = 0.f, v0wf = 0.f; bool found = false;
        for (int k = 0; k < ym_n; ++k)
            if (ym_idx[k] == i) { g = ym_g[k]; v0wf = ym_v0[k]; found = true; break; }
        if (!found) v0wf = y2zrow[i];
        sh_outz = (beta * v0wf + g) / L;
    }
    __syncthreads();
    if (tid < Z) {
        float o = (tid == zv) ? sh_outz
                : y2z[(size_t)tid * (size_t)Y + sh_winf] / fmaxf(sqrtf(nry[tid]), EPSN);
        out[tid] = o;
    }
    if (tid == 0) out[Z] = sh_actn;
}

extern "C" void kernel_launch(void* const* d_in, const int* in_sizes, int n_in,
                              void* d_out, int out_size, void* d_ws, size_t ws_size,
                              hipStream_t stream) {
    const float* x    = (const float*)d_in[0];
    const int*   z    = (const int*)d_in[1];
    const int*   pit  = (const int*)d_in[2];
    const float* x2y  = (const float*)d_in[3];
    const float* z2y  = (const float*)d_in[4];
    const float* y2z  = (const float*)d_in[5];
    const float* agey = (const float*)d_in[6];
    const float* agez = (const float*)d_in[7];
    const float* thr  = (const float*)d_in[8];
    const int X = in_sizes[0];   // 4096
    const int Y = in_sizes[6];   // 16384
    const int Z = in_sizes[7];   // 100

    float* ws = (float*)d_ws;
    float* dotx = ws;                       // Y
    float* nw2  = ws + (size_t)Y;           // Y
    float* valz = ws + 2*(size_t)Y;         // Y
    float* nz2  = ws + 3*(size_t)Y;         // Y
    float* nry  = ws + 4*(size_t)Y;         // Z (pad to 128)
    float* xn2  = ws + 4*(size_t)Y + 128;   // 1
    int*   cnti = (int*)(ws + 4*(size_t)Y + 129);
    float* ypw  = ws + 4*(size_t)Y + 256;   // Y
    float* cAw  = ws + 5*(size_t)Y + 256;   // Y
    float* chv  = ws + 6*(size_t)Y + 256;   // NCH
    int*   chi  = (int*)(ws + 6*(size_t)Y + 384);
    float* chcv = ws + 6*(size_t)Y + 512;
    int*   chci = (int*)(ws + 6*(size_t)Y + 640);
    float* out  = (float*)d_out;

    const int NBZ = Y / 4;
    const int grid_prep = NBZ + Z + Y + 1;
    hipLaunchKernelGGL(k_prep, dim3(grid_prep), dim3(256), 0, stream,
                       x2y, z2y, y2z, z, x, dotx, nw2, valz, nz2, nry, xn2, cnti, X, Y, Z);
    hipLaunchKernelGGL(k_combine, dim3(Y / CHUNK), dim3(NTL), 0, stream,
                       agey, dotx, nw2, valz, nz2, xn2, ypw, cAw, chv, chi, chcv, chci, cnti);
    hipLaunchKernelGGL(k_loop, dim3(1), dim3(NTL), 0, stream,
                       z, pit, y2z, agey, agez, thr, valz, nz2, nry,
                       ypw, cAw, chv, chi, chcv, chci, cnti, out, Y, Z);
}